// Round 5
// baseline (274.857 us; speedup 1.0000x reference)
//
#include <hip/hip_runtime.h>
#include <float.h>

#define NN 50000
#define NE 800000
#define FD 64
#define NG 64
#define SCAN_B 256
#define NBLK ((NN + SCAN_B - 1) / SCAN_B)   // 196

typedef __attribute__((ext_vector_type(8))) short short8;
typedef __attribute__((ext_vector_type(8))) float float8;
typedef __attribute__((ext_vector_type(4))) float f32x4;

// ---------- bf16 helpers (RNE) ----------
__device__ inline unsigned short f2bf(float f) {
    unsigned u = __float_as_uint(f);
    u += 0x7fffu + ((u >> 16) & 1u);
    return (unsigned short)(u >> 16);
}
__device__ inline float bf2f(unsigned short h) {
    return __uint_as_float(((unsigned)h) << 16);
}
__device__ inline float bf_lo(unsigned u) { return __uint_as_float(u << 16); }
__device__ inline float bf_hi(unsigned u) { return __uint_as_float(u & 0xffff0000u); }

// ---------- monotonic float<->uint encoding for atomic max ----------
__device__ inline unsigned encf(float f) {
    unsigned u = __float_as_uint(f);
    return (u & 0x80000000u) ? ~u : (u | 0x80000000u);
}
__device__ inline float decf(unsigned e) {
    unsigned u = (e & 0x80000000u) ? (e ^ 0x80000000u) : ~e;
    return __uint_as_float(u);
}

// ---------- init: cnt = 0, gmax = enc(-inf) ----------
__global__ void k_init(int* __restrict__ cnt, unsigned* __restrict__ gmax) {
    int i = blockIdx.x * blockDim.x + threadIdx.x;
    if (i < NN) cnt[i] = 0;
    if (i < NG * FD) gmax[i] = encf(-FLT_MAX);
}

__global__ void k_cnt(const int* __restrict__ dst, int* __restrict__ cnt) {
    int i = blockIdx.x * blockDim.x + threadIdx.x;
    if (i < NE) atomicAdd(&cnt[dst[i]], 1);
}

// ---------- scan1 (+ dis folded in) ----------
__global__ void k_scan1(const int* __restrict__ cnt, int* __restrict__ rp,
                        int* __restrict__ bsum, float* __restrict__ dis) {
    __shared__ int tmp[SCAN_B];
    int b = blockIdx.x, t = threadIdx.x;
    int i = b * SCAN_B + t;
    int v = (i < NN) ? cnt[i] : 0;
    if (i < NN) dis[i] = rsqrtf((float)v + 1.0f);   // +1 self loop
    tmp[t] = v;
    __syncthreads();
    for (int off = 1; off < SCAN_B; off <<= 1) {
        int add = (t >= off) ? tmp[t - off] : 0;
        __syncthreads();
        tmp[t] += add;
        __syncthreads();
    }
    if (i < NN) rp[i] = tmp[t] - v;
    if (t == SCAN_B - 1) bsum[b] = tmp[t];
}

__global__ void k_scan2(int* __restrict__ bsum) {
    __shared__ int tmp[256];
    int t = threadIdx.x;
    int v = (t < NBLK) ? bsum[t] : 0;
    tmp[t] = v;
    __syncthreads();
    for (int off = 1; off < 256; off <<= 1) {
        int add = (t >= off) ? tmp[t - off] : 0;
        __syncthreads();
        tmp[t] += add;
        __syncthreads();
    }
    if (t < NBLK) bsum[t] = tmp[t] - v;
}

__global__ void k_scan3(int* __restrict__ rp, const int* __restrict__ bsum,
                        int* __restrict__ cnt) {
    int i = blockIdx.x * blockDim.x + threadIdx.x;
    if (i < NN) {
        rp[i] += bsum[i / SCAN_B];
        cnt[i] = 0;                           // becomes fill cursor
    }
    if (i == 0) rp[NN] = NE;
}

__global__ void k_fill(const int* __restrict__ src, const int* __restrict__ dst,
                       const int* __restrict__ rp, int* __restrict__ cur,
                       int* __restrict__ esrc) {
    int e = blockIdx.x * blockDim.x + threadIdx.x;
    if (e < NE) {
        int d = dst[e];
        int p = rp[d] + atomicAdd(&cur[d], 1);
        esrc[p] = src[e];
    }
}

// ---------- MFMA GEMM: HsB[r,:] = bf16( dis[r] * (A[r,:] @ W) ) ----------
// SPLIT_A=1: A is f32 (hi/lo bf16 split, 3 MFMAs). SPLIT_A=0: A is bf16 (2 MFMAs).
// 16x16x32 MFMA; A row = lane&15, k = (lane>>4)*8+j (same bijection for B).
// D: row=(lane>>4)*4+r, col=lane&15 [HW-verified mapping].
template<int SPLIT_A>
__global__ __launch_bounds__(256) void k_gemm_mfma(const float* __restrict__ Af,
                                                   const unsigned short* __restrict__ Ab,
                                                   const float* __restrict__ W,
                                                   const float* __restrict__ dis,
                                                   unsigned short* __restrict__ HsB) {
    __shared__ unsigned short WtHi[4096];
    __shared__ unsigned short WtLo[4096];
    for (int i = threadIdx.x; i < 4096; i += 256) {
        int k = i >> 6, n = i & 63;
        float w = W[i];                        // W[k][n]
        unsigned short hi = f2bf(w);
        WtHi[n * 64 + k] = hi;
        WtLo[n * 64 + k] = f2bf(w - bf2f(hi));
    }
    __syncthreads();
    int lane = threadIdx.x & 63;
    int m  = lane & 15;    // A-row / D-col
    int kg = lane >> 4;    // k group
    short8 bh[4][2], bl[4][2];
#pragma unroll
    for (int t = 0; t < 4; ++t)
#pragma unroll
        for (int c = 0; c < 2; ++c) {
            int n  = 16 * t + m;
            int k0 = 32 * c + kg * 8;
            bh[t][c] = *(const short8*)&WtHi[n * 64 + k0];
            bl[t][c] = *(const short8*)&WtLo[n * 64 + k0];
        }
    int wid = (blockIdx.x * blockDim.x + threadIdx.x) >> 6;
    int nw  = (gridDim.x * blockDim.x) >> 6;
    for (int tile = wid; tile < NN / 16; tile += nw) {   // NN = 16*3125 exactly
        int r0 = tile * 16;
        f32x4 z = {0.f, 0.f, 0.f, 0.f};
        f32x4 acc0 = z, acc1 = z, acc2 = z, acc3 = z;
#pragma unroll
        for (int c = 0; c < 2; ++c) {
            short8 ah, al;
            if (SPLIT_A) {
                float8 xv = *(const float8*)(Af + (size_t)(r0 + m) * FD + 32 * c + kg * 8);
#pragma unroll
                for (int j = 0; j < 8; ++j) {
                    unsigned short hi = f2bf(xv[j]);
                    ah[j] = (short)hi;
                    al[j] = (short)f2bf(xv[j] - bf2f(hi));
                }
            } else {
                ah = *(const short8*)(Ab + (size_t)(r0 + m) * FD + 32 * c + kg * 8);
            }
            acc0 = __builtin_amdgcn_mfma_f32_16x16x32_bf16(ah, bh[0][c], acc0, 0, 0, 0);
            acc0 = __builtin_amdgcn_mfma_f32_16x16x32_bf16(ah, bl[0][c], acc0, 0, 0, 0);
            acc1 = __builtin_amdgcn_mfma_f32_16x16x32_bf16(ah, bh[1][c], acc1, 0, 0, 0);
            acc1 = __builtin_amdgcn_mfma_f32_16x16x32_bf16(ah, bl[1][c], acc1, 0, 0, 0);
            acc2 = __builtin_amdgcn_mfma_f32_16x16x32_bf16(ah, bh[2][c], acc2, 0, 0, 0);
            acc2 = __builtin_amdgcn_mfma_f32_16x16x32_bf16(ah, bl[2][c], acc2, 0, 0, 0);
            acc3 = __builtin_amdgcn_mfma_f32_16x16x32_bf16(ah, bh[3][c], acc3, 0, 0, 0);
            acc3 = __builtin_amdgcn_mfma_f32_16x16x32_bf16(ah, bl[3][c], acc3, 0, 0, 0);
            if (SPLIT_A) {
                acc0 = __builtin_amdgcn_mfma_f32_16x16x32_bf16(al, bh[0][c], acc0, 0, 0, 0);
                acc1 = __builtin_amdgcn_mfma_f32_16x16x32_bf16(al, bh[1][c], acc1, 0, 0, 0);
                acc2 = __builtin_amdgcn_mfma_f32_16x16x32_bf16(al, bh[2][c], acc2, 0, 0, 0);
                acc3 = __builtin_amdgcn_mfma_f32_16x16x32_bf16(al, bh[3][c], acc3, 0, 0, 0);
            }
        }
#pragma unroll
        for (int r = 0; r < 4; ++r) {
            int row = r0 + kg * 4 + r;
            float dd = dis[row];
            size_t base = (size_t)row * FD;
            HsB[base + 16 * 0 + m] = f2bf(dd * acc0[r]);
            HsB[base + 16 * 1 + m] = f2bf(dd * acc1[r]);
            HsB[base + 16 * 2 + m] = f2bf(dd * acc2[r]);
            HsB[base + 16 * 3 + m] = f2bf(dd * acc3[r]);
        }
    }
}

// ---------- gather: 2 nodes per wave, bf16 rows (128 B), uint = 2 feats/lane ----------
// v = dis[d] * (HsB[d,:] + sum_s HsB[s,:]) + bias
// MODE 0: Obf[d,:] = bf16(relu(v))   MODE 1: gmax[batch[d],:] = max(., v)
template<int MODE>
__global__ __launch_bounds__(256) void k_gather(const int* __restrict__ rp,
                                                const int* __restrict__ esrc,
                                                const float* __restrict__ dis,
                                                const unsigned short* __restrict__ HsB,
                                                const float* __restrict__ bias,
                                                unsigned short* __restrict__ Obf,
                                                const int* __restrict__ batch,
                                                unsigned* __restrict__ gmax) {
    int gtid  = blockIdx.x * blockDim.x + threadIdx.x;
    int wave  = gtid >> 6;
    int lane  = threadIdx.x & 63;
    int half  = lane >> 5;        // which node of the pair
    int l     = lane & 31;        // feature pair index: feats {2l, 2l+1}
    int nwave = (gridDim.x * blockDim.x) >> 6;
    float be = bias[2 * l], bo = bias[2 * l + 1];
    for (int pair = wave; pair < NN / 2; pair += nwave) {
        int d = pair * 2 + half;
        int beg = rp[d], end = rp[d + 1];
        unsigned us = *(const unsigned*)(HsB + (size_t)d * FD + 2 * l);
        float e0 = bf_lo(us), f0 = bf_hi(us);   // self-loop (pre-scaled)
        float e1 = 0.f, e2 = 0.f, e3 = 0.f, f1 = 0.f, f2 = 0.f, f3 = 0.f;
        int j = beg;
        for (; j + 4 <= end; j += 4) {
            int s0 = esrc[j], s1 = esrc[j + 1], s2 = esrc[j + 2], s3 = esrc[j + 3];
            unsigned u0 = *(const unsigned*)(HsB + (size_t)s0 * FD + 2 * l);
            unsigned u1 = *(const unsigned*)(HsB + (size_t)s1 * FD + 2 * l);
            unsigned u2 = *(const unsigned*)(HsB + (size_t)s2 * FD + 2 * l);
            unsigned u3 = *(const unsigned*)(HsB + (size_t)s3 * FD + 2 * l);
            e0 += bf_lo(u0); f0 += bf_hi(u0);
            e1 += bf_lo(u1); f1 += bf_hi(u1);
            e2 += bf_lo(u2); f2 += bf_hi(u2);
            e3 += bf_lo(u3); f3 += bf_hi(u3);
        }
        for (; j < end; ++j) {
            unsigned u = *(const unsigned*)(HsB + (size_t)esrc[j] * FD + 2 * l);
            e0 += bf_lo(u); f0 += bf_hi(u);
        }
        float dd = dis[d];
        float ve = fmaf(dd, (e0 + e1) + (e2 + e3), be);
        float vf = fmaf(dd, (f0 + f1) + (f2 + f3), bo);
        if (MODE == 0) {
            unsigned pk = (unsigned)f2bf(fmaxf(ve, 0.f)) |
                          ((unsigned)f2bf(fmaxf(vf, 0.f)) << 16);
            *(unsigned*)(Obf + (size_t)d * FD + 2 * l) = pk;
        } else {
            int g = batch[d];
            atomicMax(&gmax[g * FD + 2 * l], encf(ve));
            atomicMax(&gmax[g * FD + 2 * l + 1], encf(vf));
        }
    }
}

// ---------- final: out[g,c] = sum_f gmax[g,f] * Wlin[f,c] + blin[c] ----------
__global__ __launch_bounds__(128) void k_final(const unsigned* __restrict__ gmax,
                                               const float* __restrict__ Wlin,
                                               const float* __restrict__ blin,
                                               float* __restrict__ out) {
    __shared__ float G[NG * FD];
    for (int i = threadIdx.x; i < NG * FD; i += 128) G[i] = decf(gmax[i]);
    __syncthreads();
    int t = threadIdx.x;
    int g = t >> 1, c = t & 1;
    float acc = blin[c];
#pragma unroll
    for (int f = 0; f < 64; ++f) acc = fmaf(G[g * 64 + f], Wlin[f * 2 + c], acc);
    out[g * 2 + c] = acc;
}

extern "C" void kernel_launch(void* const* d_in, const int* in_sizes, int n_in,
                              void* d_out, int out_size, void* d_ws, size_t ws_size,
                              hipStream_t stream) {
    const float* x     = (const float*)d_in[0];
    const int*   eidx  = (const int*)d_in[1];
    const int*   batch = (const int*)d_in[2];
    const float* W1    = (const float*)d_in[3];
    const float* b1    = (const float*)d_in[4];
    const float* W2    = (const float*)d_in[5];
    const float* b2    = (const float*)d_in[6];
    const float* Wlin  = (const float*)d_in[7];
    const float* blin  = (const float*)d_in[8];
    float* out = (float*)d_out;

    const int* src = eidx;
    const int* dst = eidx + NE;

    char* ws = (char*)d_ws;
    size_t off = 0;
    auto alloc = [&](size_t bytes) { char* p = ws + off; off += (bytes + 255) & ~size_t(255); return p; };
    int*            cnt  = (int*)alloc(NN * 4);
    float*          dis  = (float*)alloc(NN * 4);
    int*            rp   = (int*)alloc((NN + 1) * 4);
    int*            bsum = (int*)alloc(NBLK * 4);
    int*            esrc = (int*)alloc(NE * 4);                    // 3.2 MB
    unsigned*       gmax = (unsigned*)alloc(NG * FD * 4);
    unsigned short* HsB  = (unsigned short*)alloc((size_t)NN * FD * 2);  // 6.4 MB
    unsigned short* Obf  = (unsigned short*)alloc((size_t)NN * FD * 2);  // 6.4 MB

    const int B = 256;
    const int gN = (NN + B - 1) / B;
    const int gE = (NE + B - 1) / B;
    const int gemmBlocks   = 512;    // 2048 waves, ~1.5 row-tiles each
    const int gatherBlocks = 2048;   // 8192 waves, ~3 node-pairs each

    // ---- CSR build + norm ----
    k_init<<<gN, B, 0, stream>>>(cnt, gmax);
    k_cnt<<<gE, B, 0, stream>>>(dst, cnt);
    k_scan1<<<NBLK, SCAN_B, 0, stream>>>(cnt, rp, bsum, dis);
    k_scan2<<<1, 256, 0, stream>>>(bsum);
    k_scan3<<<gN, B, 0, stream>>>(rp, bsum, cnt);
    k_fill<<<gE, B, 0, stream>>>(src, dst, rp, cnt, esrc);

    // ---- layer 1: HsB = bf16(dis * (x @ W1)) ; Obf = bf16(relu(gather + b1)) ----
    k_gemm_mfma<1><<<gemmBlocks, B, 0, stream>>>(x, nullptr, W1, dis, HsB);
    k_gather<0><<<gatherBlocks, B, 0, stream>>>(rp, esrc, dis, HsB, b1, Obf, batch, gmax);

    // ---- layer 2: HsB = bf16(dis * (Obf @ W2)) ; gmax = segmax(gather + b2) ----
    k_gemm_mfma<0><<<gemmBlocks, B, 0, stream>>>(nullptr, Obf, W2, dis, HsB);
    k_gather<1><<<gatherBlocks, B, 0, stream>>>(rp, esrc, dis, HsB, b2, nullptr, batch, gmax);

    // ---- head ----
    k_final<<<1, 128, 0, stream>>>(gmax, Wlin, blin, out);
}

// Round 6
// 240.938 us; speedup vs baseline: 1.1408x; 1.1408x over previous
//
#include <hip/hip_runtime.h>
#include <float.h>

#define NN 50000
#define NE 800000
#define FD 64
#define NG 64
#define SCAN_B 256
#define NBLK ((NN + SCAN_B - 1) / SCAN_B)   // 196

typedef __attribute__((ext_vector_type(8))) short short8;
typedef __attribute__((ext_vector_type(8))) float float8;
typedef __attribute__((ext_vector_type(4))) float f32x4;

// ---------- bf16 helpers (RNE) ----------
__device__ inline unsigned short f2bf(float f) {
    unsigned u = __float_as_uint(f);
    u += 0x7fffu + ((u >> 16) & 1u);
    return (unsigned short)(u >> 16);
}
__device__ inline float bf2f(unsigned short h) {
    return __uint_as_float(((unsigned)h) << 16);
}

// ---------- monotonic float<->uint encoding for atomic max ----------
__device__ inline unsigned encf(float f) {
    unsigned u = __float_as_uint(f);
    return (u & 0x80000000u) ? ~u : (u | 0x80000000u);
}
__device__ inline float decf(unsigned e) {
    unsigned u = (e & 0x80000000u) ? (e ^ 0x80000000u) : ~e;
    return __uint_as_float(u);
}

// ---------- init: cnt = 0, gmax = enc(-inf) ----------
__global__ void k_init(int* __restrict__ cnt, unsigned* __restrict__ gmax) {
    int i = blockIdx.x * blockDim.x + threadIdx.x;
    if (i < NN) cnt[i] = 0;
    if (i < NG * FD) gmax[i] = encf(-FLT_MAX);
}

__global__ void k_cnt(const int* __restrict__ dst, int* __restrict__ cnt) {
    int i = blockIdx.x * blockDim.x + threadIdx.x;
    if (i < NE) atomicAdd(&cnt[dst[i]], 1);
}

// ---------- scan1 (+ dis folded in) ----------
__global__ void k_scan1(const int* __restrict__ cnt, int* __restrict__ rp,
                        int* __restrict__ bsum, float* __restrict__ dis) {
    __shared__ int tmp[SCAN_B];
    int b = blockIdx.x, t = threadIdx.x;
    int i = b * SCAN_B + t;
    int v = (i < NN) ? cnt[i] : 0;
    if (i < NN) dis[i] = rsqrtf((float)v + 1.0f);   // +1 self loop
    tmp[t] = v;
    __syncthreads();
    for (int off = 1; off < SCAN_B; off <<= 1) {
        int add = (t >= off) ? tmp[t - off] : 0;
        __syncthreads();
        tmp[t] += add;
        __syncthreads();
    }
    if (i < NN) rp[i] = tmp[t] - v;
    if (t == SCAN_B - 1) bsum[b] = tmp[t];
}

__global__ void k_scan2(int* __restrict__ bsum) {
    __shared__ int tmp[256];
    int t = threadIdx.x;
    int v = (t < NBLK) ? bsum[t] : 0;
    tmp[t] = v;
    __syncthreads();
    for (int off = 1; off < 256; off <<= 1) {
        int add = (t >= off) ? tmp[t - off] : 0;
        __syncthreads();
        tmp[t] += add;
        __syncthreads();
    }
    if (t < NBLK) bsum[t] = tmp[t] - v;
}

__global__ void k_scan3(int* __restrict__ rp, const int* __restrict__ bsum,
                        int* __restrict__ cnt) {
    int i = blockIdx.x * blockDim.x + threadIdx.x;
    if (i < NN) {
        rp[i] += bsum[i / SCAN_B];
        cnt[i] = 0;                           // becomes fill cursor
    }
    if (i == 0) rp[NN] = NE;
}

__global__ void k_fill(const int* __restrict__ src, const int* __restrict__ dst,
                       const int* __restrict__ rp, int* __restrict__ cur,
                       int* __restrict__ esrc) {
    int e = blockIdx.x * blockDim.x + threadIdx.x;
    if (e < NE) {
        int d = dst[e];
        int p = rp[d] + atomicAdd(&cur[d], 1);
        esrc[p] = src[e];
    }
}

// ---------- MFMA GEMM: HsB[r,:] = bf16( dis[r] * (A[r,:] @ W) ) ----------
// SPLIT_A=1: A f32 (hi/lo split, 3 MFMAs). SPLIT_A=0: A bf16 (2 MFMAs).
template<int SPLIT_A>
__global__ __launch_bounds__(256) void k_gemm_mfma(const float* __restrict__ Af,
                                                   const unsigned short* __restrict__ Ab,
                                                   const float* __restrict__ W,
                                                   const float* __restrict__ dis,
                                                   unsigned short* __restrict__ HsB) {
    __shared__ unsigned short WtHi[4096];
    __shared__ unsigned short WtLo[4096];
    for (int i = threadIdx.x; i < 4096; i += 256) {
        int k = i >> 6, n = i & 63;
        float w = W[i];                        // W[k][n]
        unsigned short hi = f2bf(w);
        WtHi[n * 64 + k] = hi;
        WtLo[n * 64 + k] = f2bf(w - bf2f(hi));
    }
    __syncthreads();
    int lane = threadIdx.x & 63;
    int m  = lane & 15;    // A-row / D-col
    int kg = lane >> 4;    // k group
    short8 bh[4][2], bl[4][2];
#pragma unroll
    for (int t = 0; t < 4; ++t)
#pragma unroll
        for (int c = 0; c < 2; ++c) {
            int n  = 16 * t + m;
            int k0 = 32 * c + kg * 8;
            bh[t][c] = *(const short8*)&WtHi[n * 64 + k0];
            bl[t][c] = *(const short8*)&WtLo[n * 64 + k0];
        }
    int wid = (blockIdx.x * blockDim.x + threadIdx.x) >> 6;
    int nw  = (gridDim.x * blockDim.x) >> 6;
    for (int tile = wid; tile < NN / 16; tile += nw) {   // NN = 16*3125 exactly
        int r0 = tile * 16;
        f32x4 z = {0.f, 0.f, 0.f, 0.f};
        f32x4 acc0 = z, acc1 = z, acc2 = z, acc3 = z;
#pragma unroll
        for (int c = 0; c < 2; ++c) {
            short8 ah, al;
            if (SPLIT_A) {
                float8 xv = *(const float8*)(Af + (size_t)(r0 + m) * FD + 32 * c + kg * 8);
#pragma unroll
                for (int j = 0; j < 8; ++j) {
                    unsigned short hi = f2bf(xv[j]);
                    ah[j] = (short)hi;
                    al[j] = (short)f2bf(xv[j] - bf2f(hi));
                }
            } else {
                ah = *(const short8*)(Ab + (size_t)(r0 + m) * FD + 32 * c + kg * 8);
            }
            acc0 = __builtin_amdgcn_mfma_f32_16x16x32_bf16(ah, bh[0][c], acc0, 0, 0, 0);
            acc0 = __builtin_amdgcn_mfma_f32_16x16x32_bf16(ah, bl[0][c], acc0, 0, 0, 0);
            acc1 = __builtin_amdgcn_mfma_f32_16x16x32_bf16(ah, bh[1][c], acc1, 0, 0, 0);
            acc1 = __builtin_amdgcn_mfma_f32_16x16x32_bf16(ah, bl[1][c], acc1, 0, 0, 0);
            acc2 = __builtin_amdgcn_mfma_f32_16x16x32_bf16(ah, bh[2][c], acc2, 0, 0, 0);
            acc2 = __builtin_amdgcn_mfma_f32_16x16x32_bf16(ah, bl[2][c], acc2, 0, 0, 0);
            acc3 = __builtin_amdgcn_mfma_f32_16x16x32_bf16(ah, bh[3][c], acc3, 0, 0, 0);
            acc3 = __builtin_amdgcn_mfma_f32_16x16x32_bf16(ah, bl[3][c], acc3, 0, 0, 0);
            if (SPLIT_A) {
                acc0 = __builtin_amdgcn_mfma_f32_16x16x32_bf16(al, bh[0][c], acc0, 0, 0, 0);
                acc1 = __builtin_amdgcn_mfma_f32_16x16x32_bf16(al, bh[1][c], acc1, 0, 0, 0);
                acc2 = __builtin_amdgcn_mfma_f32_16x16x32_bf16(al, bh[2][c], acc2, 0, 0, 0);
                acc3 = __builtin_amdgcn_mfma_f32_16x16x32_bf16(al, bh[3][c], acc3, 0, 0, 0);
            }
        }
#pragma unroll
        for (int r = 0; r < 4; ++r) {
            int row = r0 + kg * 4 + r;
            float dd = dis[row];
            size_t base = (size_t)row * FD;
            HsB[base + 16 * 0 + m] = f2bf(dd * acc0[r]);
            HsB[base + 16 * 1 + m] = f2bf(dd * acc1[r]);
            HsB[base + 16 * 2 + m] = f2bf(dd * acc2[r]);
            HsB[base + 16 * 3 + m] = f2bf(dd * acc3[r]);
        }
    }
}

// ---------- gather: one wave per node, lane = feature, 16 loads in flight ----------
// v = dis[d] * (HsB[d,:] + sum_s HsB[s,:]) + bias
// MODE 0: Obf[d,:] = bf16(relu(v))   MODE 1: gmax[batch[d],:] = max(., v)
template<int MODE>
__global__ __launch_bounds__(256) void k_gather(const int* __restrict__ rp,
                                                const int* __restrict__ esrc,
                                                const float* __restrict__ dis,
                                                const unsigned short* __restrict__ HsB,
                                                const float* __restrict__ bias,
                                                unsigned short* __restrict__ Obf,
                                                const int* __restrict__ batch,
                                                unsigned* __restrict__ gmax) {
    int gtid  = blockIdx.x * blockDim.x + threadIdx.x;
    int wave  = gtid >> 6;
    int f     = threadIdx.x & 63;     // feature index
    int nwave = (gridDim.x * blockDim.x) >> 6;
    float bf_ = bias[f];
    for (int d = wave; d < NN; d += nwave) {
        int beg = rp[d], end = rp[d + 1];
        float a0 = bf2f(HsB[(size_t)d * FD + f]);   // self-loop (pre-scaled)
        float a1 = 0.f, a2 = 0.f, a3 = 0.f, a4 = 0.f, a5 = 0.f, a6 = 0.f, a7 = 0.f;
        float a8 = 0.f, a9 = 0.f, aA = 0.f, aB = 0.f, aC = 0.f, aD = 0.f, aE = 0.f, aF = 0.f;
        int j = beg;
#define EDGE(K, ACC) { int s = esrc[j + K]; ACC += bf2f(HsB[(size_t)s * FD + f]); }
        for (; j + 16 <= end; j += 16) {
            EDGE(0, a0)  EDGE(1, a1)  EDGE(2, a2)  EDGE(3, a3)
            EDGE(4, a4)  EDGE(5, a5)  EDGE(6, a6)  EDGE(7, a7)
            EDGE(8, a8)  EDGE(9, a9)  EDGE(10, aA) EDGE(11, aB)
            EDGE(12, aC) EDGE(13, aD) EDGE(14, aE) EDGE(15, aF)
        }
        if (j + 8 <= end) {
            EDGE(0, a0) EDGE(1, a1) EDGE(2, a2) EDGE(3, a3)
            EDGE(4, a4) EDGE(5, a5) EDGE(6, a6) EDGE(7, a7)
            j += 8;
        }
        if (j + 4 <= end) {
            EDGE(0, a8) EDGE(1, a9) EDGE(2, aA) EDGE(3, aB)
            j += 4;
        }
        for (; j < end; ++j) EDGE(0, aC)
#undef EDGE
        float s0 = ((a0 + a1) + (a2 + a3)) + ((a4 + a5) + (a6 + a7));
        float s1 = ((a8 + a9) + (aA + aB)) + ((aC + aD) + (aE + aF));
        float v = fmaf(dis[d], s0 + s1, bf_);
        if (MODE == 0) {
            Obf[(size_t)d * FD + f] = f2bf(fmaxf(v, 0.0f));
        } else {
            atomicMax(&gmax[batch[d] * FD + f], encf(v));
        }
    }
}

// ---------- final: out[g,c] = sum_f gmax[g,f] * Wlin[f,c] + blin[c] ----------
__global__ __launch_bounds__(128) void k_final(const unsigned* __restrict__ gmax,
                                               const float* __restrict__ Wlin,
                                               const float* __restrict__ blin,
                                               float* __restrict__ out) {
    __shared__ float G[NG * FD];
    for (int i = threadIdx.x; i < NG * FD; i += 128) G[i] = decf(gmax[i]);
    __syncthreads();
    int t = threadIdx.x;
    int g = t >> 1, c = t & 1;
    float acc = blin[c];
#pragma unroll
    for (int f = 0; f < 64; ++f) acc = fmaf(G[g * 64 + f], Wlin[f * 2 + c], acc);
    out[g * 2 + c] = acc;
}

extern "C" void kernel_launch(void* const* d_in, const int* in_sizes, int n_in,
                              void* d_out, int out_size, void* d_ws, size_t ws_size,
                              hipStream_t stream) {
    const float* x     = (const float*)d_in[0];
    const int*   eidx  = (const int*)d_in[1];
    const int*   batch = (const int*)d_in[2];
    const float* W1    = (const float*)d_in[3];
    const float* b1    = (const float*)d_in[4];
    const float* W2    = (const float*)d_in[5];
    const float* b2    = (const float*)d_in[6];
    const float* Wlin  = (const float*)d_in[7];
    const float* blin  = (const float*)d_in[8];
    float* out = (float*)d_out;

    const int* src = eidx;
    const int* dst = eidx + NE;

    char* ws = (char*)d_ws;
    size_t off = 0;
    auto alloc = [&](size_t bytes) { char* p = ws + off; off += (bytes + 255) & ~size_t(255); return p; };
    int*            cnt  = (int*)alloc(NN * 4);
    float*          dis  = (float*)alloc(NN * 4);
    int*            rp   = (int*)alloc((NN + 1) * 4);
    int*            bsum = (int*)alloc(NBLK * 4);
    int*            esrc = (int*)alloc(NE * 4);                    // 3.2 MB
    unsigned*       gmax = (unsigned*)alloc(NG * FD * 4);
    unsigned short* HsB  = (unsigned short*)alloc((size_t)NN * FD * 2);  // 6.4 MB
    unsigned short* Obf  = (unsigned short*)alloc((size_t)NN * FD * 2);  // 6.4 MB

    const int B = 256;
    const int gN = (NN + B - 1) / B;
    const int gE = (NE + B - 1) / B;
    const int gemmBlocks   = 512;    // 2048 waves
    const int gatherBlocks = 2048;   // 8192 waves, ~6 nodes each

    // ---- CSR build + norm ----
    k_init<<<gN, B, 0, stream>>>(cnt, gmax);
    k_cnt<<<gE, B, 0, stream>>>(dst, cnt);
    k_scan1<<<NBLK, SCAN_B, 0, stream>>>(cnt, rp, bsum, dis);
    k_scan2<<<1, 256, 0, stream>>>(bsum);
    k_scan3<<<gN, B, 0, stream>>>(rp, bsum, cnt);
    k_fill<<<gE, B, 0, stream>>>(src, dst, rp, cnt, esrc);

    // ---- layer 1: HsB = bf16(dis * (x @ W1)) ; Obf = bf16(relu(gather + b1)) ----
    k_gemm_mfma<1><<<gemmBlocks, B, 0, stream>>>(x, nullptr, W1, dis, HsB);
    k_gather<0><<<gatherBlocks, B, 0, stream>>>(rp, esrc, dis, HsB, b1, Obf, batch, gmax);

    // ---- layer 2: HsB = bf16(dis * (Obf @ W2)) ; gmax = segmax(gather + b2) ----
    k_gemm_mfma<0><<<gemmBlocks, B, 0, stream>>>(nullptr, Obf, W2, dis, HsB);
    k_gather<1><<<gatherBlocks, B, 0, stream>>>(rp, esrc, dis, HsB, b2, nullptr, batch, gmax);

    // ---- head ----
    k_final<<<1, 128, 0, stream>>>(gmax, Wlin, blin, out);
}